// Round 4
// baseline (1559.480 us; speedup 1.0000x reference)
//
#include <hip/hip_runtime.h>
#include <hip/hip_cooperative_groups.h>

namespace cg = cooperative_groups;

// CubicalLayer: gather birth/death filtration values from a flattened 512^3
// volume (512 MB) via 8M persistence-pair indices; zero pairs with
// death == birth (min_pers = 0.0).
//
// History: direct random gather = 750 us total (kernel work ~400 us,
// ~1 TB/s effective: DRAM row-miss bound). Materialized binning (R2: +253)
// and L3 chunk-warming (R3: +182) both paid more in extra traffic than the
// locality gained.
//
// This version: window-synchronized cooperative gather, ZERO extra traffic.
//   - One kernel. Each thread loads 32 indices into registers (idx read once),
//     gathers into 32 register slots across 8 windows of X (64 MB each),
//     grid.sync() between windows.
//   - With all in-flight gathers confined to one 64 MB window, each DRAM
//     (pseudo-channel, bank) sees only ~2-8 distinct rows -> the memory
//     controllers' row-hit-first reordering converts the random stream into
//     mostly row hits. No cache warming, no intermediates.
//   - Pair keep/zero filter applied in-register; out written once, coalesced.
//   - grid.sync() is a performance hint only: no cross-block data dependency,
//     so correctness never depends on barrier semantics.
//   - If cooperative launch is unavailable/fails -> verified direct fallback.

typedef int   v4i __attribute__((ext_vector_type(4)));
typedef float v4f __attribute__((ext_vector_type(4)));

#define NWIN        8      // 512 MB / 8 = 64 MB windows
#define COOP_BLOCKS_MAX 1024   // 4 blocks/CU x 256 CUs co-resident @ <=128 VGPR
#define CCHUNK      8      // v4i chunks per thread -> 32 indices, 32 values

__global__ __launch_bounds__(256, 4) void gather_windows_coop(
    const float* __restrict__ X,
    const int* __restrict__ idx0,   // 2*P0 interleaved (birth, death)
    const int* __restrict__ idx1,   // 2*P1
    float* __restrict__ out,
    int n4_0, int n4_total, int wchunk, int nX)
{
    constexpr int C = CCHUNK;
    cg::grid_group grid = cg::this_grid();

    const int tid    = blockIdx.x * blockDim.x + threadIdx.x;
    const int stride = gridDim.x * blockDim.x;

    // ---- load indices once, keep in registers ----
    int  c[C];
    v4i  ij[C];
    bool ok[C];
    #pragma unroll
    for (int j = 0; j < C; ++j) {
        c[j]  = tid + j * stride;
        ok[j] = c[j] < n4_total;
        int cc = ok[j] ? c[j] : 0;
        const v4i* p = (cc < n4_0)
            ? reinterpret_cast<const v4i*>(idx0) + cc
            : reinterpret_cast<const v4i*>(idx1) + (cc - n4_0);
        ij[j] = *p;
    }

    float v[C][4];
    #pragma unroll
    for (int j = 0; j < C; ++j) {
        v[j][0] = 0.0f; v[j][1] = 0.0f; v[j][2] = 0.0f; v[j][3] = 0.0f;
    }

    // ---- windowed gather: all blocks sweep X together ----
    int lo = 0;
    for (int w = 0; w < NWIN; ++w) {
        int hi = lo + wchunk;
        if (hi > nX) hi = nX;
        const unsigned span = (unsigned)(hi - lo);
        #pragma unroll
        for (int j = 0; j < C; ++j) {
            #pragma unroll
            for (int k = 0; k < 4; ++k) {
                int id = (k == 0) ? ij[j].x : (k == 1) ? ij[j].y
                       : (k == 2) ? ij[j].z : ij[j].w;
                if ((unsigned)(id - lo) < span)
                    v[j][k] = X[id];     // row-hit-friendly: window-confined
            }
        }
        lo = hi;
        if (w != NWIN - 1) grid.sync();  // perf hint only (no data dep)
    }

    // ---- fused pair filter + single coalesced output write ----
    #pragma unroll
    for (int j = 0; j < C; ++j) {
        bool k0 = v[j][1] != v[j][0];   // |d-b| > 0  <=>  d != b (no NaNs)
        bool k1 = v[j][3] != v[j][2];
        v4f o;
        o.x = k0 ? v[j][0] : 0.0f;
        o.y = k0 ? v[j][1] : 0.0f;
        o.z = k1 ? v[j][2] : 0.0f;
        o.w = k1 ? v[j][3] : 0.0f;
        if (ok[j])
            *(reinterpret_cast<v4f*>(out) + c[j]) = o;
    }
}

// ---------------- fallback: direct gather (harness-verified, 750 us) -------
__global__ __launch_bounds__(256) void gather_diagram_kernel(
    const float* __restrict__ X,
    const int* __restrict__ idx0,
    const int* __restrict__ idx1,
    float* __restrict__ out,
    int n4_0, int n4_total)
{
    constexpr int C = 4;
    const int tid    = blockIdx.x * blockDim.x + threadIdx.x;
    const int stride = gridDim.x * blockDim.x;

    int  c[C];
    v4i  ij[C];
    bool ok[C];
    #pragma unroll
    for (int j = 0; j < C; ++j) {
        c[j]  = tid + j * stride;
        ok[j] = c[j] < n4_total;
        int cc = ok[j] ? c[j] : 0;
        const v4i* p = (cc < n4_0)
            ? reinterpret_cast<const v4i*>(idx0) + cc
            : reinterpret_cast<const v4i*>(idx1) + (cc - n4_0);
        ij[j] = *p;
    }

    float v[C][4];
    #pragma unroll
    for (int j = 0; j < C; ++j) {
        v[j][0] = X[ij[j].x];
        v[j][1] = X[ij[j].y];
        v[j][2] = X[ij[j].z];
        v[j][3] = X[ij[j].w];
    }

    #pragma unroll
    for (int j = 0; j < C; ++j) {
        bool k0 = v[j][1] != v[j][0];
        bool k1 = v[j][3] != v[j][2];
        v4f o;
        o.x = k0 ? v[j][0] : 0.0f;
        o.y = k0 ? v[j][1] : 0.0f;
        o.z = k1 ? v[j][2] : 0.0f;
        o.w = k1 ? v[j][3] : 0.0f;
        if (ok[j])
            *(reinterpret_cast<v4f*>(out) + c[j]) = o;
    }
}

static void launch_direct(const float* X, const int* idx0, const int* idx1,
                          float* out, int n4_0, int n4_total,
                          hipStream_t stream) {
    constexpr int C = 4, BLOCK = 256;
    const int threads_needed = (n4_total + C - 1) / C;
    const int blocks = (threads_needed + BLOCK - 1) / BLOCK;
    if (blocks > 0)
        gather_diagram_kernel<<<blocks, BLOCK, 0, stream>>>(
            X, idx0, idx1, out, n4_0, n4_total);
}

extern "C" void kernel_launch(void* const* d_in, const int* in_sizes, int n_in,
                              void* d_out, int out_size, void* d_ws, size_t ws_size,
                              hipStream_t stream) {
    const float* X        = (const float*)d_in[0];
    const int*   indices0 = (const int*)d_in[1];
    const int*   indices1 = (const int*)d_in[2];
    float*       out      = (float*)d_out;

    const int nX       = in_sizes[0];   // floats in X (512^3 = 2^27)
    const int n0       = in_sizes[1];   // int32 elements in idx0
    const int n1       = in_sizes[2];   // int32 elements in idx1
    const int n4_0     = n0 / 4;
    const int n4_total = (n0 + n1) / 4;

    if ((n0 & 3) || (n1 & 3) || n4_total <= 0 || nX <= 0) {
        launch_direct(X, indices0, indices1, out, n4_0, n4_total, stream);
        return;
    }

    constexpr int BLOCK = 256;
    const int threads_needed = (n4_total + CCHUNK - 1) / CCHUNK;
    int blocks = (threads_needed + BLOCK - 1) / BLOCK;
    if (blocks > COOP_BLOCKS_MAX) {
        // capacity exceeded for co-resident cooperative grid -> direct
        launch_direct(X, indices0, indices1, out, n4_0, n4_total, stream);
        return;
    }

    int wchunk = (nX + NWIN - 1) / NWIN;
    void* args[] = {
        (void*)&X, (void*)&indices0, (void*)&indices1, (void*)&out,
        (void*)&n4_0, (void*)&n4_total, (void*)&wchunk, (void*)&nX
    };
    hipError_t err = hipLaunchCooperativeKernel(
        (const void*)gather_windows_coop,
        dim3(blocks), dim3(BLOCK), args, 0, stream);
    if (err != hipSuccess) {
        (void)hipGetLastError();  // clear
        launch_direct(X, indices0, indices1, out, n4_0, n4_total, stream);
    }
}